// Round 5
// baseline (281.985 us; speedup 1.0000x reference)
//
#include <hip/hip_runtime.h>

// Problem constants (from reference setup_inputs):
//   x: (1, 3, 128, 128) fp32
//   w: (3, 124, 124, 25, 5, 5) fp32
//   q: (3, 124, 124, 25, 5, 5) fp32
//   out: (1, 3, 124, 124, 25) fp32
// out[o] = log( prod_{k=0..24} (1.1 + atan(10*(x_k*w_k - q_k))/pi) )
//
// R8 design: R3's zero-sync register kernel + NT loads + anti-sink fence.
// Ladder so far: R3 regs/no-barrier=86.7, R4 LDS/drain=87.5, R5 persistent=92.5
//   (pre-NT: all pinned by the ~2.6 TB/s cached/L3-hit path wall),
// R6 = R4+NT -> <67us (out of rocprof top-5), R7 = R5+NT -> bench total +20us
//   vs R6 (245.6 vs 225.5): persistent lockstep HURTS post-NT too.
// Lesson: in this delivery-bound regime, independent self-paced entities beat
// barrier-synced pipelines. Endpoint of that trend = R3's structure (zero
// barriers, zero LDS, zero block lifecycle), whose two failure causes are now
// both addressed:
//   (i)  cached-path wall -> __builtin_nontemporal_load (nt bit) on the
//        zero-reuse w/q streams (the R6 win, ~20us);
//   (ii) VGPR_Count=36 proved the allocator SANK the upfront loads ->
//        sched_barrier(0) is a hard fence: all 29 loads issue before any
//        compute. ~110 VGPR live -> 4 waves/SIMD, 16 waves/CU, ~200 KB of
//        NT loads in flight per CU (>> ~10 KB bandwidth-delay product).
// Readout is asymmetric: dendrite re-appearing in the rocprof top-5 (>67us)
// means this failed -> revert to R6. VGPR_Count is the fence-held check.

#define IMG   128
#define OUT   124
#define NUM   25
#define NOUT  (3 * OUT * OUT * NUM)            // 1,153,200 outputs
#define OPB   256

// 16-byte NT load at dword (not 16B) alignment: gfx950 global loads only need
// dword alignment; aligned(4) on the vector type keeps the IR honest so the
// backend can't assume align-16.
typedef float f4nt __attribute__((ext_vector_type(4), aligned(4)));

// Minimax atan, |err| ~ 2e-6 over all inputs. Range-reduce with v_rcp_f32.
__device__ __forceinline__ float fast_atan(float z) {
    float az  = __builtin_fabsf(z);
    float r   = __builtin_amdgcn_rcpf(az);
    bool  big = az > 1.0f;
    float t   = big ? r : az;                   // t in [0, 1]
    float s   = t * t;
    float p   =                     -0.01172120f;
    p = __builtin_fmaf(p, s,         0.05265332f);
    p = __builtin_fmaf(p, s,        -0.11643287f);
    p = __builtin_fmaf(p, s,         0.19354346f);
    p = __builtin_fmaf(p, s,        -0.33262347f);
    p = __builtin_fmaf(p, s,         0.99997726f);
    float a = t * p;
    a = big ? (1.57079632679489662f - a) : a;
    return __builtin_copysignf(a, z);
}

__global__ __launch_bounds__(OPB) void dendrite_kernel(
    const float* __restrict__ x,
    const float* __restrict__ w,
    const float* __restrict__ q,
    float* __restrict__ out)
{
    const int o = blockIdx.x * OPB + threadIdx.x;
    if (o >= NOUT) return;

    int rem = o / NUM;                 // (c*OUT + i)*OUT + j
    const int j = rem % OUT;  rem /= OUT;
    const int i = rem % OUT;
    const int c = rem / OUT;

    const float* wp = w + (long long)o * NUM;      // 100 B per lane
    const float* qp = q + (long long)o * NUM;
    const float* xp = x + ((long long)c * IMG + i) * IMG + j;

    // ---- Issue ALL loads up front. w/q: zero-reuse streams -> NT (evict-
    // first, skips the slow L3-hit path). x: 196 KB, heavy reuse -> cached.
    float wv[NUM], qv[NUM], xv[NUM];
    #pragma unroll
    for (int g = 0; g < 6; ++g) {
        f4nt a = __builtin_nontemporal_load((const f4nt*)(wp + 4 * g));
        wv[4*g+0] = a.x; wv[4*g+1] = a.y; wv[4*g+2] = a.z; wv[4*g+3] = a.w;
    }
    wv[24] = __builtin_nontemporal_load(wp + 24);
    #pragma unroll
    for (int g = 0; g < 6; ++g) {
        f4nt a = __builtin_nontemporal_load((const f4nt*)(qp + 4 * g));
        qv[4*g+0] = a.x; qv[4*g+1] = a.y; qv[4*g+2] = a.z; qv[4*g+3] = a.w;
    }
    qv[24] = __builtin_nontemporal_load(qp + 24);
    #pragma unroll
    for (int u = 0; u < 5; ++u) {
        float4 a;
        __builtin_memcpy(&a, xp + u * IMG, sizeof(float4)); // dword-aligned ok
        xv[5*u+0] = a.x; xv[5*u+1] = a.y; xv[5*u+2] = a.z; xv[5*u+3] = a.w;
        xv[5*u+4] = xp[u * IMG + 4];
    }

    // Hard scheduling fence: nothing may cross (mask 0). This is the anti-sink
    // fix for R3's VGPR_Count=36 — all 29 loads are issued above this line,
    // so the wave holds ~12.8 KB of NT traffic in flight while it waits.
    __builtin_amdgcn_sched_barrier(0);

    // ---- Pure VALU: 25 independent terms, 2 product chains for ILP ----
    float prod0 = 1.0f, prod1 = 1.0f;
    #pragma unroll
    for (int k = 0; k < NUM; ++k) {
        const float z = 10.0f * __builtin_fmaf(xv[k], wv[k], -qv[k]);
        const float a = fast_atan(z);
        const float term = __builtin_fmaf(a, 0.31830988618379067f, 1.1f);
        if (k & 1) prod1 *= term; else prod0 *= term;
    }
    // prod in (~0.6^25, ~1.6^25) = (2.8e-6, 1.3e5): fp32-safe, single log.
    __builtin_nontemporal_store(__logf(prod0 * prod1), &out[o]);
}

extern "C" void kernel_launch(void* const* d_in, const int* in_sizes, int n_in,
                              void* d_out, int out_size, void* d_ws, size_t ws_size,
                              hipStream_t stream) {
    const float* x = (const float*)d_in[0];
    const float* w = (const float*)d_in[1];
    const float* q = (const float*)d_in[2];
    float* out = (float*)d_out;

    const int grid = (NOUT + OPB - 1) / OPB;   // 4505 blocks
    dendrite_kernel<<<grid, OPB, 0, stream>>>(x, w, q, out);
}

// Round 6
// 229.959 us; speedup vs baseline: 1.2262x; 1.2262x over previous
//
#include <hip/hip_runtime.h>

// Problem constants (from reference setup_inputs):
//   x: (1, 3, 128, 128) fp32
//   w: (3, 124, 124, 25, 5, 5) fp32
//   q: (3, 124, 124, 25, 5, 5) fp32
//   out: (1, 3, 124, 124, 25) fp32
// out[o] = log( prod_{k=0..24} (1.1 + atan(10*(x_k*w_k - q_k))/pi) )
//
// R9 design: R6's NT LDS-DMA staging, decoupled to PER-WAVE granularity.
// Ladder: R3 regs=86.7 / R4 LDS-drain=87.5 / R5 persistent=92.5 (all pre-NT,
// pinned by the ~2.6 TB/s cached-path wall) -> R6=R4+NT: dendrite <67us (best,
// bench 225.5) -> R7 persistent+NT: +20us (lockstep hurts) -> R8 register+NT:
// 99us, VGPR=44 (sched_barrier(0) cannot stop IR-level load sinking; register
// NT scatter dead end).
// Gradient across R7(1 entity/CU) -> R6(3) says: looser coupling wins in this
// delivery-bound regime. Endpoint: vmcnt is PER-WAVE state and global_load_lds
// completion is tracked by the issuing wave's vmcnt, so if each wave stages
// its OWN 64 outputs' w/q into its OWN LDS region and reads back only what it
// wrote, NO __syncthreads is needed at all. 12 independent self-paced wave
// pipelines per CU (3 blocks x 4 waves, LDS-bound), each: 14 contiguous NT
// DMA -> x register loads -> one vmcnt(0) on its own traffic -> compute ->
// NT store -> die. DMA contiguity kept; nothing for the allocator to sink.

#define IMG   128
#define OUT   124
#define NUM   25
#define NOUT  (3 * OUT * OUT * NUM)        // 1,153,200 outputs
#define WQF   (NOUT * NUM)                 // 28,830,000 floats in w (and q)
#define OPB   256                          // threads per block

// Minimax atan, |err| ~ 2e-6 over all inputs. Range-reduce with v_rcp_f32.
__device__ __forceinline__ float fast_atan(float z) {
    float az  = __builtin_fabsf(z);
    float r   = __builtin_amdgcn_rcpf(az);
    bool  big = az > 1.0f;
    float t   = big ? r : az;                   // t in [0, 1]
    float s   = t * t;
    float p   =                     -0.01172120f;
    p = __builtin_fmaf(p, s,         0.05265332f);
    p = __builtin_fmaf(p, s,        -0.11643287f);
    p = __builtin_fmaf(p, s,         0.19354346f);
    p = __builtin_fmaf(p, s,        -0.33262347f);
    p = __builtin_fmaf(p, s,         0.99997726f);
    float a = t * p;
    a = big ? (1.57079632679489662f - a) : a;
    return __builtin_copysignf(a, z);
}

// Async global->LDS, NON-TEMPORAL (aux=2 -> `nt`: evict-first; w/q have zero
// reuse -- caching them was the R0-R5 ~2.6 TB/s wall). LDS dest = wave-uniform
// base + lane*size (HW semantics); global src per-lane. Size is a literal.
__device__ __forceinline__ void copy16_lds_nt(const float* g, float* l) {
    __builtin_amdgcn_global_load_lds(
        (const __attribute__((address_space(1))) unsigned int*)g,
        (__attribute__((address_space(3))) unsigned int*)l, 16, 0, 2);
}
__device__ __forceinline__ void copy4_lds_nt(const float* g, float* l) {
    __builtin_amdgcn_global_load_lds(
        (const __attribute__((address_space(1))) unsigned int*)g,
        (__attribute__((address_space(3))) unsigned int*)l, 4, 0, 2);
}

__global__ __launch_bounds__(OPB) void dendrite_kernel(
    const float* __restrict__ x,
    const float* __restrict__ w,
    const float* __restrict__ q,
    float* __restrict__ out)
{
    __shared__ float w_lds[OPB * NUM];     // 25.6 KB
    __shared__ float q_lds[OPB * NUM];     // 25.6 KB  (51.2 KB -> 3 blocks/CU)

    const int tid   = threadIdx.x;
    const int lane  = tid & 63;
    const int wvb   = tid & ~63;                    // wave's base thread
    const int owave = blockIdx.x * OPB + wvb;       // wave's first output
    if (owave >= NOUT) return;                      // wave fully OOB (uniform)

    // ---- Per-wave staging: this wave's 64 outputs = 1600 contiguous floats
    // of w (and of q). 6x(64 lanes x 16B) + 1x(64 lanes x 4B) = 14 NT DMA,
    // each instruction covering a contiguous 1 KB. Per-lane src clamp keeps
    // the last wave's overhang in-bounds (dest garbage is store-guarded).
    const int wq_base = owave * NUM;                // < 28.8M, fits int
    float* wl = &w_lds[wvb * NUM];                  // wave-private LDS region
    float* ql = &q_lds[wvb * NUM];
    #pragma unroll
    for (int r = 0; r < 6; ++r) {
        const int f  = r * 256;                     // wave-uniform float offset
        const int sf = min(wq_base + f + lane * 4, WQF - 4);
        copy16_lds_nt(w + sf, wl + f);
        copy16_lds_nt(q + sf, ql + f);
    }
    {
        const int sf = min(wq_base + 1536 + lane, WQF - 1);
        copy4_lds_nt(w + sf, wl + 1536);
        copy4_lds_nt(q + sf, ql + 1536);
    }

    // ---- x patch -> registers (196 KB, heavy reuse: cached loads), issued
    // while the wave's 12.8 KB of NT DMA is in flight.
    const int o  = owave + (tid & 63);
    const int oc = min(o, NOUT - 1);                // clamp tail addressing
    int rem = oc / NUM;                             // (c*OUT + i)*OUT + j
    const int j = rem % OUT;  rem /= OUT;
    const int i = rem % OUT;
    const int c = rem / OUT;
    const float* xp = x + (c * IMG + i) * IMG + j;

    float xv[NUM];
    #pragma unroll
    for (int u = 0; u < 5; ++u) {
        float4 a;
        __builtin_memcpy(&a, xp + u * IMG, sizeof(float4));  // dword-aligned ok
        xv[5*u+0] = a.x; xv[5*u+1] = a.y; xv[5*u+2] = a.z; xv[5*u+3] = a.w;
        xv[5*u+4] = xp[u * IMG + 4];
    }

    // One per-wave wait on the wave's OWN traffic (DMA + x loads). No
    // __syncthreads anywhere: this wave reads only LDS it wrote itself.
    asm volatile("s_waitcnt vmcnt(0)" ::: "memory");

    // ---- Pure VALU: LDS reads at odd float-stride 25 (2 lanes/bank = free).
    if (o < NOUT) {
        const float* wt = &w_lds[tid * NUM];
        const float* qt = &q_lds[tid * NUM];
        float prod0 = 1.0f, prod1 = 1.0f;
        #pragma unroll
        for (int k = 0; k < NUM; ++k) {
            const float z = 10.0f * __builtin_fmaf(xv[k], wt[k], -qt[k]);
            const float a = fast_atan(z);
            const float term = __builtin_fmaf(a, 0.31830988618379067f, 1.1f);
            if (k & 1) prod1 *= term; else prod0 *= term;
        }
        // prod in (~0.6^25, ~1.6^25): fp32-safe, single log.
        __builtin_nontemporal_store(__logf(prod0 * prod1), &out[o]);
    }
}

extern "C" void kernel_launch(void* const* d_in, const int* in_sizes, int n_in,
                              void* d_out, int out_size, void* d_ws, size_t ws_size,
                              hipStream_t stream) {
    const float* x = (const float*)d_in[0];
    const float* w = (const float*)d_in[1];
    const float* q = (const float*)d_in[2];
    float* out = (float*)d_out;

    const int grid = (NOUT + OPB - 1) / OPB;   // 4505 blocks
    dendrite_kernel<<<grid, OPB, 0, stream>>>(x, w, q, out);
}